// Round 20
// baseline (143.848 us; speedup 1.0000x reference)
//
#include <hip/hip_runtime.h>

typedef unsigned short u16;
typedef unsigned int u32;
typedef __bf16 bf16_t;
typedef bf16_t bf16x8 __attribute__((ext_vector_type(8)));
typedef bf16_t bf16x4_t __attribute__((ext_vector_type(4)));
typedef float f32x4 __attribute__((ext_vector_type(4)));
typedef unsigned short ushort8_t __attribute__((ext_vector_type(8)));

#define S_LEN 2048
#define DM 1024
#define NH 16
#define HDIM 64
#define TSTR 136  // gemm epilogue-transpose LDS row stride in u16

// ---- helpers ----
__device__ __forceinline__ u16 f2b(float f) {
  u32 u = __builtin_bit_cast(u32, f);
  u32 r = (u + 0x7FFFu + ((u >> 16) & 1u)) >> 16;  // RNE
  return (u16)r;
}

__device__ __forceinline__ void gload16(const void* g, void* l) {
  __builtin_amdgcn_global_load_lds((const __attribute__((address_space(1))) void*)g,
                                   (__attribute__((address_space(3))) void*)l,
                                   16, 0, 0);
}

__device__ __forceinline__ bf16x8 ld_bf8(const u16* p) {
  return *reinterpret_cast<const bf16x8*>(p);
}

// ---- [R][64]-u16 tile staging (128B rows -> XOR swizzle load-bearing, G4):
// pre-swizzled SOURCE column, linear LDS dest (rule #21); read with same XOR. ----
__device__ __forceinline__ void stage_rows64(const u16* __restrict__ base, int stride,
                                             u16* __restrict__ dst, int tid, int nchunk) {
#pragma unroll
  for (int i = 0; i < 4; ++i) {
    if (i < nchunk) {
      int ci = i * 256 + tid;
      int row = ci >> 3, col = ci & 7;
      gload16(base + (size_t)row * stride + ((col ^ (row & 7)) << 3), dst + ci * 8);
    }
  }
}
__device__ __forceinline__ void stage_tile256(const u16* __restrict__ base, int stride,
                                              u16* __restrict__ dst, int tid) {
  stage_rows64(base, stride, dst, tid, 2);
}
__device__ __forceinline__ bf16x8 ld_swz64(const u16* lds, int row, int chunk) {
  return ld_bf8(lds + row * 64 + ((chunk ^ (row & 7)) << 3));
}

// ---- kernel 1: x f32 -> bf16 ----
__global__ __launch_bounds__(256) void k_cvt(const float* __restrict__ in, u16* __restrict__ out) {
  int i = (blockIdx.x * 256 + threadIdx.x) * 4;
  float4 v = *reinterpret_cast<const float4*>(in + i);
  ushort4 o = make_ushort4(f2b(v.x), f2b(v.y), f2b(v.z), f2b(v.w));
  *reinterpret_cast<ushort4*>(out + i) = o;
}

// ---- kernel 2: all three W [K][N] f32 -> Wt [3*N][K] bf16 in one launch ----
__global__ __launch_bounds__(256) void k_wt3(const float* __restrict__ Wq, const float* __restrict__ Wk,
                                             const float* __restrict__ Wv, u16* __restrict__ Wt) {
  __shared__ float t[32][33];
  const float* W = (blockIdx.z == 0) ? Wq : (blockIdx.z == 1) ? Wk : Wv;
  u16* dst = Wt + (size_t)blockIdx.z * (DM * DM);
  int n0 = blockIdx.x * 32, k0 = blockIdx.y * 32;
  int tx = threadIdx.x & 31, ty = threadIdx.x >> 5;
#pragma unroll
  for (int i = 0; i < 32; i += 8)
    t[ty + i][tx] = W[(size_t)(k0 + ty + i) * DM + n0 + tx];
  __syncthreads();
#pragma unroll
  for (int i = 0; i < 32; i += 8)
    dst[(size_t)(n0 + ty + i) * DM + k0 + tx] = f2b(t[tx][ty + i]);
}

// ---- GEMM core: BK=64, 16 K-iters, single buffer, swizzled [128][64] tiles. ----
template <bool TRANSPOSED>
__device__ __forceinline__ void gemm_loop(const u16* __restrict__ Ag, const u16* __restrict__ Bg,
                                          u16* __restrict__ At, u16* __restrict__ Bt,
                                          f32x4 (&acc)[4][4], int tid, int l15, int lg,
                                          int wm, int wn) {
  for (int kt = 0; kt < 16; ++kt) {
    int kk = kt * 64;
    stage_rows64(Ag + kk, DM, At, tid, 4);
    stage_rows64(Bg + kk, DM, Bt, tid, 4);
    __syncthreads();
#pragma unroll
    for (int ks = 0; ks < 2; ++ks) {
      bf16x8 af[4], bfr[4];
#pragma unroll
      for (int mi = 0; mi < 4; ++mi)
        af[mi] = ld_swz64(At, wm * 64 + mi * 16 + l15, ks * 4 + lg);
#pragma unroll
      for (int ni = 0; ni < 4; ++ni)
        bfr[ni] = ld_swz64(Bt, wn * 64 + ni * 16 + l15, ks * 4 + lg);
#pragma unroll
      for (int mi = 0; mi < 4; ++mi)
#pragma unroll
        for (int ni = 0; ni < 4; ++ni) {
          if (TRANSPOSED)
            acc[mi][ni] = __builtin_amdgcn_mfma_f32_16x16x32_bf16(bfr[ni], af[mi], acc[mi][ni], 0, 0, 0);
          else
            acc[mi][ni] = __builtin_amdgcn_mfma_f32_16x16x32_bf16(af[mi], bfr[ni], acc[mi][ni], 0, 0, 0);
        }
    }
    __syncthreads();
  }
}

// ---- kernel 3: fused QKV GEMM, 128x128 tile, BK=64, 4 waves, 2D natural grid.
// (256,3) = R14-R18 proven config (R19's (256,4) was ~+2us — reverted). ----
__global__ __launch_bounds__(256, 3) void k_gemm(const u16* __restrict__ Xb, const u16* __restrict__ Wt_all,
                                                 u16* __restrict__ Out_all, u16* __restrict__ Vt,
                                                 float qscale) {
  __shared__ __attribute__((aligned(16))) u16 smem[128 * TSTR];  // 34.8 KB
  u16* At = smem;           // 128x64
  u16* Bt = smem + 8192;    // 128x64
  int bx = blockIdx.x, by = blockIdx.y;
  int n0g = bx * 128, m0 = by * 128;
  int which = n0g >> 10;              // uniform per block (128 | 1024)
  int n0 = n0g & 1023;
  int tid = threadIdx.x;
  int lane = tid & 63, w = tid >> 6;
  int l15 = lane & 15, lg = lane >> 4;
  int wm = w >> 1, wn = w & 1;        // 2x2 waves, wave tile 64x64

  const u16* Ag = Xb + (size_t)m0 * DM;
  const u16* Bg = Wt_all + (size_t)n0g * DM;

  f32x4 acc[4][4] = {};
  u16* T = smem;
  int b = m0 >> 11, s0 = m0 & 2047;
  int base_h = n0 >> 6;

  if (which < 2) {
    gemm_loop<true>(Ag, Bg, At, Bt, acc, tid, l15, lg, wm, wn);
    float scale = (which == 0) ? qscale : 1.0f;
    u16* Out = Out_all + (size_t)which * (size_t)(4 * NH * S_LEN * HDIM);
#pragma unroll
    for (int mi = 0; mi < 4; ++mi) {
#pragma unroll
      for (int ni = 0; ni < 4; ++ni) {
        ushort4 w4 = make_ushort4(f2b(acc[mi][ni][0] * scale), f2b(acc[mi][ni][1] * scale),
                                  f2b(acc[mi][ni][2] * scale), f2b(acc[mi][ni][3] * scale));
        *reinterpret_cast<ushort4*>(T + (wm * 64 + mi * 16 + l15) * TSTR +
                                    wn * 64 + ni * 16 + lg * 4) = w4;
      }
    }
    __syncthreads();
#pragma unroll
    for (int pass = 0; pass < 8; ++pass) {
      int row = pass * 16 + (tid >> 4);
      int col = (tid & 15) * 8;
      ushort8_t v = *reinterpret_cast<const ushort8_t*>(T + row * TSTR + col);
      int h = base_h + (col >> 6), hd = col & 63;
      *reinterpret_cast<ushort8_t*>(Out + ((size_t)(b * NH + h) * S_LEN + s0 + row) * HDIM + hd) = v;
    }
  } else {
    gemm_loop<false>(Ag, Bg, At, Bt, acc, tid, l15, lg, wm, wn);
#pragma unroll
    for (int mi = 0; mi < 4; ++mi) {
#pragma unroll
      for (int ni = 0; ni < 4; ++ni) {
        ushort4 w4 = make_ushort4(f2b(acc[mi][ni][0]), f2b(acc[mi][ni][1]),
                                  f2b(acc[mi][ni][2]), f2b(acc[mi][ni][3]));
        *reinterpret_cast<ushort4*>(T + (wn * 64 + ni * 16 + l15) * TSTR +
                                    wm * 64 + mi * 16 + lg * 4) = w4;
      }
    }
    __syncthreads();
#pragma unroll
    for (int pass = 0; pass < 8; ++pass) {
      int row = pass * 16 + (tid >> 4);
      int col = (tid & 15) * 8;
      ushort8_t v = *reinterpret_cast<const ushort8_t*>(T + row * TSTR + col);
      int h = base_h + (row >> 6), hd = row & 63;
      *reinterpret_cast<ushort8_t*>(Vt + ((size_t)((b * NH + h) * HDIM + hd)) * S_LEN + s0 + col) = v;
    }
  }
}

// ---- softmax for one strip: raw exp2 (static exponent), optional causal mask,
// pack -> per-wave P LDS -> read back A-layout fragments. ----
__device__ __forceinline__ void softmax_p(bool diag, int k0, int qa, f32x4 (&sc)[4],
                                          u16* __restrict__ Pw, int l15, int lg, int psw,
                                          float& ls, bf16x8& pf0, bf16x8& pf1) {
  if (diag) {
#pragma unroll
    for (int kb = 0; kb < 4; ++kb) {
      bf16x4_t pw;
#pragma unroll
      for (int r = 0; r < 4; ++r) {
        int key = k0 + kb * 16 + lg * 4 + r;
        float e = __builtin_amdgcn_exp2f(sc[kb][r]);
        e = (key > qa) ? 0.f : e;
        ls += e;
        pw[r] = (bf16_t)e;
      }
      *reinterpret_cast<bf16x4_t*>(Pw + l15 * 64 + ((kb * 16 + lg * 4) ^ psw)) = pw;
    }
  } else {
#pragma unroll
    for (int kb = 0; kb < 4; ++kb) {
      bf16x4_t pw;
#pragma unroll
      for (int r = 0; r < 4; ++r) {
        float e = __builtin_amdgcn_exp2f(sc[kb][r]);
        ls += e;
        pw[r] = (bf16_t)e;
      }
      *reinterpret_cast<bf16x4_t*>(Pw + l15 * 64 + ((kb * 16 + lg * 4) ^ psw)) = pw;
    }
  }
  asm volatile("" ::: "memory");  // P write -> read order (per-wave, DS in-order)
  pf0 = ld_bf8(Pw + l15 * 64 + ((lg * 8) ^ psw));
  pf1 = ld_bf8(Pw + l15 * 64 + ((32 + lg * 8) ^ psw));
}

__device__ __forceinline__ void strip_out(float* __restrict__ out, int b, int h, int qrow,
                                          int l15, int lg, f32x4 (&o)[4], float ls) {
  ls += __shfl_xor(ls, 16);
  ls += __shfl_xor(ls, 32);
  float lsr[4];
#pragma unroll
  for (int r = 0; r < 4; ++r) lsr[r] = __shfl(ls, lg * 4 + r);
#pragma unroll
  for (int r = 0; r < 4; ++r) {
    float inv = 1.f / lsr[r];
    int row = qrow + lg * 4 + r;
#pragma unroll
    for (int n = 0; n < 4; ++n)
      out[((size_t)b * S_LEN + row) * DM + h * HDIM + n * 16 + l15] = o[n][r] * inv;
  }
}

// ---- kernel 5: causal flash attention, DUAL-STRIP FUSED with SHARED K/V frags.
// The kernel is LDS-throughput-bound (26 DS instr/wave-tile ~ 270cy x 16 waves
// = measured 4500cy/CU/tile-round). kf and vf are identical for both strips ->
// load once, feed both strips' MFMAs: block DS reads drop ~23%.
// Per tile: vmcnt(0); bar1; stage K(t+1); QK-dual (shared kf); vf<-Vd (shared);
// lgkmcnt(0); bar2; stage V(t+1); softmaxB->pfB; softmaxA->pfA (same Pw,
// per-wave DS in-order); PV-dual (shared vf).
// (256,3): 170-reg budget for peak ~150 (qf32+sc32+vf32+pf16+misc; o in AGPR).
// Canary: WRITE_SIZE must stay 32.8 MB. ----
__global__ __launch_bounds__(256, 3) void k_attn(const u16* __restrict__ Qb, const u16* __restrict__ Kb,
                                                 const u16* __restrict__ Vtb, float* __restrict__ out) {
  __shared__ u16 Kd[2][64 * 64];
  __shared__ u16 Vd[64 * 64];
  __shared__ u16 Plds[4][16 * 64];
  int j = blockIdx.x;
  int m = j >> 3;
  int xr = m & 15;
  int x = ((j >> 8) & 1) ? (15 - xr) : xr;   // balance co-resident blocks
  int bh = (j & 7) + 8 * (m >> 4);
  int tid = threadIdx.x, lane = tid & 63, w = tid >> 6;
  int b = bh >> 4, h = bh & 15;
  int l15 = lane & 15, lg = lane >> 4;
  int psw = (l15 & 7) << 3;
  const u16* Qp = Qb + (size_t)bh * S_LEN * HDIM;
  const u16* Kp = Kb + (size_t)bh * S_LEN * HDIM;
  const u16* Vp = Vtb + (size_t)bh * HDIM * S_LEN;
  u16* Pw = Plds[w];

  int qrowA = x * 64 + w * 16;          // strip A: q-tile x, active kt <= x
  int qrowB = (31 - x) * 64 + w * 16;   // strip B: q-tile 31-x, active all kt
  int qaA = qrowA + l15, qaB = qrowB + l15;
  bf16x8 qfA0 = ld_bf8(Qp + (size_t)(qrowA + l15) * HDIM + lg * 8);
  bf16x8 qfA1 = ld_bf8(Qp + (size_t)(qrowA + l15) * HDIM + 32 + lg * 8);
  bf16x8 qfB0 = ld_bf8(Qp + (size_t)(qrowB + l15) * HDIM + lg * 8);
  bf16x8 qfB1 = ld_bf8(Qp + (size_t)(qrowB + l15) * HDIM + 32 + lg * 8);
  f32x4 oA[4] = {}, oB[4] = {};
  float lsA = 0.f, lsB = 0.f;

  int nt = 32 - x;  // strip B's tile count; B diag at kt==nt-1, A diag at kt==x

  stage_tile256(Kp, HDIM, Kd[0], tid);
  stage_tile256(Vp, S_LEN, Vd, tid);

  for (int kt = 0; kt < nt; ++kt) {
    int k0 = kt * 64;
    int cur = kt & 1;
    bool pre = (kt + 1 < nt);
    bool dual = (kt <= x);
    // barrier1: K(t) (issued iter t-1) and V(t) (issued mid-iter t-1) landed
    asm volatile("s_waitcnt vmcnt(0)" ::: "memory");
    __builtin_amdgcn_sched_barrier(0);
    __builtin_amdgcn_s_barrier();
    __builtin_amdgcn_sched_barrier(0);
    if (pre)
      stage_tile256(Kp + (size_t)(k0 + 64) * HDIM, HDIM, Kd[cur ^ 1], tid);

    // QK-dual: kf loaded ONCE, feeds both strips (swapped: lane q=l15)
    f32x4 scA[4], scB[4];
    __builtin_amdgcn_s_setprio(1);
#pragma unroll
    for (int kb = 0; kb < 4; ++kb) {
      bf16x8 kf0 = ld_swz64(Kd[cur], kb * 16 + l15, lg);
      bf16x8 kf1 = ld_swz64(Kd[cur], kb * 16 + l15, 4 + lg);
      f32x4 zB = {};
      zB = __builtin_amdgcn_mfma_f32_16x16x32_bf16(kf0, qfB0, zB, 0, 0, 0);
      scB[kb] = __builtin_amdgcn_mfma_f32_16x16x32_bf16(kf1, qfB1, zB, 0, 0, 0);
      if (dual) {
        f32x4 zA = {};
        zA = __builtin_amdgcn_mfma_f32_16x16x32_bf16(kf0, qfA0, zA, 0, 0, 0);
        scA[kb] = __builtin_amdgcn_mfma_f32_16x16x32_bf16(kf1, qfA1, zA, 0, 0, 0);
      }
    }
    __builtin_amdgcn_s_setprio(0);

    // V fragments loaded ONCE (shared by both strips' PV)
    bf16x8 vf[4][2];
#pragma unroll
    for (int n = 0; n < 4; ++n) {
      vf[n][0] = ld_swz64(Vd, n * 16 + l15, lg);
      vf[n][1] = ld_swz64(Vd, n * 16 + l15, 4 + lg);
    }
    asm volatile("s_waitcnt lgkmcnt(0)" ::: "memory");
    __builtin_amdgcn_sched_barrier(0);
    __builtin_amdgcn_s_barrier();
    __builtin_amdgcn_sched_barrier(0);
    if (pre)
      stage_tile256(Vp + k0 + 64, S_LEN, Vd, tid);  // drains at next barrier1

    // softmax + P roundtrip, B then A (same per-wave buffer; DS in-order)
    bf16x8 pfB0, pfB1, pfA0, pfA1;
    softmax_p(kt == nt - 1, k0, qaB, scB, Pw, l15, lg, psw, lsB, pfB0, pfB1);
    if (dual)
      softmax_p(kt == x, k0, qaA, scA, Pw, l15, lg, psw, lsA, pfA0, pfA1);

    // PV-dual with shared vf
    __builtin_amdgcn_s_setprio(1);
#pragma unroll
    for (int n = 0; n < 4; ++n) {
      oB[n] = __builtin_amdgcn_mfma_f32_16x16x32_bf16(pfB0, vf[n][0], oB[n], 0, 0, 0);
      oB[n] = __builtin_amdgcn_mfma_f32_16x16x32_bf16(pfB1, vf[n][1], oB[n], 0, 0, 0);
      if (dual) {
        oA[n] = __builtin_amdgcn_mfma_f32_16x16x32_bf16(pfA0, vf[n][0], oA[n], 0, 0, 0);
        oA[n] = __builtin_amdgcn_mfma_f32_16x16x32_bf16(pfA1, vf[n][1], oA[n], 0, 0, 0);
      }
    }
    __builtin_amdgcn_s_setprio(0);
  }

  strip_out(out, b, h, qrowA, l15, lg, oA, lsA);
  strip_out(out, b, h, qrowB, l15, lg, oB, lsB);
}

extern "C" void kernel_launch(void* const* d_in, const int* in_sizes, int n_in,
                              void* d_out, int out_size, void* d_ws, size_t ws_size,
                              hipStream_t stream) {
  const float* x  = (const float*)d_in[0];
  const float* Wq = (const float*)d_in[1];
  const float* Wk = (const float*)d_in[2];
  const float* Wv = (const float*)d_in[3];
  float* out = (float*)d_out;

  u16* ws  = (u16*)d_ws;
  u16* xb  = ws;                    // 8192*1024
  u16* wqt = xb + 8388608;          // 3 x 1024*1024 contiguous
  u16* Qb  = wqt + 3145728;         // Q,K each [B,H,S,HD]
  u16* Kb  = Qb + 8388608;
  u16* Vtb = Kb + 8388608;          // [B,H,HD,S] written directly by k_gemm

  const float qscale = 0.125f * 1.44269504088896f;  // 1/sqrt(64) * log2(e)

  k_cvt<<<8192, 256, 0, stream>>>(x, xb);
  k_wt3<<<dim3(32, 32, 3), 256, 0, stream>>>(Wq, Wk, Wv, wqt);
  k_gemm<<<dim3(24, 64), 256, 0, stream>>>(xb, wqt, Qb, Vtb, qscale);
  k_attn<<<1024, 256, 0, stream>>>(Qb, Kb, Vtb, out);
}

// Round 21
// 126.741 us; speedup vs baseline: 1.1350x; 1.1350x over previous
//
#include <hip/hip_runtime.h>

typedef unsigned short u16;
typedef unsigned int u32;
typedef __bf16 bf16_t;
typedef bf16_t bf16x8 __attribute__((ext_vector_type(8)));
typedef bf16_t bf16x4_t __attribute__((ext_vector_type(4)));
typedef float f32x4 __attribute__((ext_vector_type(4)));
typedef unsigned short ushort8_t __attribute__((ext_vector_type(8)));

#define S_LEN 2048
#define DM 1024
#define NH 16
#define HDIM 64
#define TSTR 136  // gemm epilogue-transpose LDS row stride in u16

// ---- helpers ----
__device__ __forceinline__ u16 f2b(float f) {
  u32 u = __builtin_bit_cast(u32, f);
  u32 r = (u + 0x7FFFu + ((u >> 16) & 1u)) >> 16;  // RNE
  return (u16)r;
}

__device__ __forceinline__ void gload16(const void* g, void* l) {
  __builtin_amdgcn_global_load_lds((const __attribute__((address_space(1))) void*)g,
                                   (__attribute__((address_space(3))) void*)l,
                                   16, 0, 0);
}

__device__ __forceinline__ bf16x8 ld_bf8(const u16* p) {
  return *reinterpret_cast<const bf16x8*>(p);
}

// ---- [R][64]-u16 tile staging (128B rows -> XOR swizzle load-bearing, G4):
// pre-swizzled SOURCE column, linear LDS dest (rule #21); read with same XOR. ----
__device__ __forceinline__ void stage_rows64(const u16* __restrict__ base, int stride,
                                             u16* __restrict__ dst, int tid, int nchunk) {
#pragma unroll
  for (int i = 0; i < 4; ++i) {
    if (i < nchunk) {
      int ci = i * 256 + tid;
      int row = ci >> 3, col = ci & 7;
      gload16(base + (size_t)row * stride + ((col ^ (row & 7)) << 3), dst + ci * 8);
    }
  }
}
__device__ __forceinline__ void stage_tile256(const u16* __restrict__ base, int stride,
                                              u16* __restrict__ dst, int tid) {
  stage_rows64(base, stride, dst, tid, 2);
}
__device__ __forceinline__ bf16x8 ld_swz64(const u16* lds, int row, int chunk) {
  return ld_bf8(lds + row * 64 + ((chunk ^ (row & 7)) << 3));
}

// ---- kernel 1: x f32 -> bf16 ----
__global__ __launch_bounds__(256) void k_cvt(const float* __restrict__ in, u16* __restrict__ out) {
  int i = (blockIdx.x * 256 + threadIdx.x) * 4;
  float4 v = *reinterpret_cast<const float4*>(in + i);
  ushort4 o = make_ushort4(f2b(v.x), f2b(v.y), f2b(v.z), f2b(v.w));
  *reinterpret_cast<ushort4*>(out + i) = o;
}

// ---- kernel 2: all three W [K][N] f32 -> Wt [3*N][K] bf16 in one launch ----
__global__ __launch_bounds__(256) void k_wt3(const float* __restrict__ Wq, const float* __restrict__ Wk,
                                             const float* __restrict__ Wv, u16* __restrict__ Wt) {
  __shared__ float t[32][33];
  const float* W = (blockIdx.z == 0) ? Wq : (blockIdx.z == 1) ? Wk : Wv;
  u16* dst = Wt + (size_t)blockIdx.z * (DM * DM);
  int n0 = blockIdx.x * 32, k0 = blockIdx.y * 32;
  int tx = threadIdx.x & 31, ty = threadIdx.x >> 5;
#pragma unroll
  for (int i = 0; i < 32; i += 8)
    t[ty + i][tx] = W[(size_t)(k0 + ty + i) * DM + n0 + tx];
  __syncthreads();
#pragma unroll
  for (int i = 0; i < 32; i += 8)
    dst[(size_t)(n0 + ty + i) * DM + k0 + tx] = f2b(t[tx][ty + i]);
}

// ---- GEMM core: BK=64, 16 K-iters, single buffer, swizzled [128][64] tiles. ----
template <bool TRANSPOSED>
__device__ __forceinline__ void gemm_loop(const u16* __restrict__ Ag, const u16* __restrict__ Bg,
                                          u16* __restrict__ At, u16* __restrict__ Bt,
                                          f32x4 (&acc)[4][4], int tid, int l15, int lg,
                                          int wm, int wn) {
  for (int kt = 0; kt < 16; ++kt) {
    int kk = kt * 64;
    stage_rows64(Ag + kk, DM, At, tid, 4);
    stage_rows64(Bg + kk, DM, Bt, tid, 4);
    __syncthreads();
#pragma unroll
    for (int ks = 0; ks < 2; ++ks) {
      bf16x8 af[4], bfr[4];
#pragma unroll
      for (int mi = 0; mi < 4; ++mi)
        af[mi] = ld_swz64(At, wm * 64 + mi * 16 + l15, ks * 4 + lg);
#pragma unroll
      for (int ni = 0; ni < 4; ++ni)
        bfr[ni] = ld_swz64(Bt, wn * 64 + ni * 16 + l15, ks * 4 + lg);
#pragma unroll
      for (int mi = 0; mi < 4; ++mi)
#pragma unroll
        for (int ni = 0; ni < 4; ++ni) {
          if (TRANSPOSED)
            acc[mi][ni] = __builtin_amdgcn_mfma_f32_16x16x32_bf16(bfr[ni], af[mi], acc[mi][ni], 0, 0, 0);
          else
            acc[mi][ni] = __builtin_amdgcn_mfma_f32_16x16x32_bf16(af[mi], bfr[ni], acc[mi][ni], 0, 0, 0);
        }
    }
    __syncthreads();
  }
}

// ---- kernel 3: fused QKV GEMM, 128x128 tile, BK=64, 4 waves, 2D natural grid.
// (256,3) proven best (R14/R15). One-pass epilogue. ----
__global__ __launch_bounds__(256, 3) void k_gemm(const u16* __restrict__ Xb, const u16* __restrict__ Wt_all,
                                                 u16* __restrict__ Out_all, u16* __restrict__ Vt,
                                                 float qscale) {
  __shared__ __attribute__((aligned(16))) u16 smem[128 * TSTR];  // 34.8 KB
  u16* At = smem;           // 128x64
  u16* Bt = smem + 8192;    // 128x64
  int bx = blockIdx.x, by = blockIdx.y;
  int n0g = bx * 128, m0 = by * 128;
  int which = n0g >> 10;              // uniform per block (128 | 1024)
  int n0 = n0g & 1023;
  int tid = threadIdx.x;
  int lane = tid & 63, w = tid >> 6;
  int l15 = lane & 15, lg = lane >> 4;
  int wm = w >> 1, wn = w & 1;        // 2x2 waves, wave tile 64x64

  const u16* Ag = Xb + (size_t)m0 * DM;
  const u16* Bg = Wt_all + (size_t)n0g * DM;

  f32x4 acc[4][4] = {};
  u16* T = smem;
  int b = m0 >> 11, s0 = m0 & 2047;
  int base_h = n0 >> 6;

  if (which < 2) {
    gemm_loop<true>(Ag, Bg, At, Bt, acc, tid, l15, lg, wm, wn);
    float scale = (which == 0) ? qscale : 1.0f;
    u16* Out = Out_all + (size_t)which * (size_t)(4 * NH * S_LEN * HDIM);
#pragma unroll
    for (int mi = 0; mi < 4; ++mi) {
#pragma unroll
      for (int ni = 0; ni < 4; ++ni) {
        ushort4 w4 = make_ushort4(f2b(acc[mi][ni][0] * scale), f2b(acc[mi][ni][1] * scale),
                                  f2b(acc[mi][ni][2] * scale), f2b(acc[mi][ni][3] * scale));
        *reinterpret_cast<ushort4*>(T + (wm * 64 + mi * 16 + l15) * TSTR +
                                    wn * 64 + ni * 16 + lg * 4) = w4;
      }
    }
    __syncthreads();
#pragma unroll
    for (int pass = 0; pass < 8; ++pass) {
      int row = pass * 16 + (tid >> 4);
      int col = (tid & 15) * 8;
      ushort8_t v = *reinterpret_cast<const ushort8_t*>(T + row * TSTR + col);
      int h = base_h + (col >> 6), hd = col & 63;
      *reinterpret_cast<ushort8_t*>(Out + ((size_t)(b * NH + h) * S_LEN + s0 + row) * HDIM + hd) = v;
    }
  } else {
    gemm_loop<false>(Ag, Bg, At, Bt, acc, tid, l15, lg, wm, wn);
#pragma unroll
    for (int mi = 0; mi < 4; ++mi) {
#pragma unroll
      for (int ni = 0; ni < 4; ++ni) {
        ushort4 w4 = make_ushort4(f2b(acc[mi][ni][0]), f2b(acc[mi][ni][1]),
                                  f2b(acc[mi][ni][2]), f2b(acc[mi][ni][3]));
        *reinterpret_cast<ushort4*>(T + (wn * 64 + ni * 16 + l15) * TSTR +
                                    wm * 64 + mi * 16 + lg * 4) = w4;
      }
    }
    __syncthreads();
#pragma unroll
    for (int pass = 0; pass < 8; ++pass) {
      int row = pass * 16 + (tid >> 4);
      int col = (tid & 15) * 8;
      ushort8_t v = *reinterpret_cast<const ushort8_t*>(T + row * TSTR + col);
      int h = base_h + (row >> 6), hd = row & 63;
      *reinterpret_cast<ushort8_t*>(Vt + ((size_t)((b * NH + h) * HDIM + hd)) * S_LEN + s0 + col) = v;
    }
  }
}

// ---- block-cooperative flash strip, 1-barrier schedule (R15 proven best).
// K AND V double-buffered, both prefetched 1 tile ahead. Per tile:
//   vmcnt(0)   <- drains loads issued a FULL iteration ago (nearly free)
//   s_barrier  <- the only barrier: makes all waves' stages visible AND proves
//                 every wave finished compute on buf[(t+1)&1]
//   stage K/V(t+1) -> buf[(t+1)&1]
//   QK -> softmax(exp2 raw) -> P (per-wave [16][64] LDS, XOR-swz) -> PV ----
__device__ __forceinline__ void attn_strip(const u16* __restrict__ Qp, const u16* __restrict__ Kp,
                                           const u16* __restrict__ Vp, float* __restrict__ out,
                                           int b, int h, int qbase, int w, int tid, int lane, int nt,
                                           u16 (*Kd)[64 * 64], u16 (*Vd)[64 * 64],
                                           u16* __restrict__ Pw) {
  int l15 = lane & 15, lg = lane >> 4;
  int qrow = qbase + w * 16;
  bf16x8 qf0 = ld_bf8(Qp + (size_t)(qrow + l15) * HDIM + lg * 8);
  bf16x8 qf1 = ld_bf8(Qp + (size_t)(qrow + l15) * HDIM + 32 + lg * 8);
  f32x4 o[4] = {};
  float ls = 0.f;
  int qa = qrow + l15;
  int psw = (l15 & 7) << 3;  // P-tile XOR swizzle (u16 units)

  stage_tile256(Kp, HDIM, Kd[0], tid);
  stage_tile256(Vp, S_LEN, Vd[0], tid);

  for (int kt = 0; kt < nt; ++kt) {
    int k0 = kt * 64;
    int cur = kt & 1;
    asm volatile("s_waitcnt vmcnt(0)" ::: "memory");
    __builtin_amdgcn_sched_barrier(0);
    __builtin_amdgcn_s_barrier();
    __builtin_amdgcn_sched_barrier(0);
    if (kt + 1 < nt) {
      stage_tile256(Kp + (size_t)(k0 + 64) * HDIM, HDIM, Kd[cur ^ 1], tid);
      stage_tile256(Vp + k0 + 64, S_LEN, Vd[cur ^ 1], tid);
    }

    // QK^T (swapped): lane holds q=l15, keys kb*16 + lg*4 + r
    f32x4 sc[4];
    __builtin_amdgcn_s_setprio(1);
#pragma unroll
    for (int kb = 0; kb < 4; ++kb) {
      bf16x8 kf0 = ld_swz64(Kd[cur], kb * 16 + l15, lg);
      bf16x8 kf1 = ld_swz64(Kd[cur], kb * 16 + l15, 4 + lg);
      f32x4 z = {};
      z = __builtin_amdgcn_mfma_f32_16x16x32_bf16(kf0, qf0, z, 0, 0, 0);
      sc[kb] = __builtin_amdgcn_mfma_f32_16x16x32_bf16(kf1, qf1, sc[kb] = z, 0, 0, 0);
    }
    __builtin_amdgcn_s_setprio(0);

    // static-exponent softmax; P -> per-wave LDS [16][64], col XOR psw
    if (kt == nt - 1) {
#pragma unroll
      for (int kb = 0; kb < 4; ++kb) {
        bf16x4_t pw;
#pragma unroll
        for (int r = 0; r < 4; ++r) {
          int key = k0 + kb * 16 + lg * 4 + r;
          float e = __builtin_amdgcn_exp2f(sc[kb][r]);
          e = (key > qa) ? 0.f : e;
          ls += e;
          pw[r] = (bf16_t)e;
        }
        *reinterpret_cast<bf16x4_t*>(Pw + l15 * 64 + ((kb * 16 + lg * 4) ^ psw)) = pw;
      }
    } else {
#pragma unroll
      for (int kb = 0; kb < 4; ++kb) {
        bf16x4_t pw;
#pragma unroll
        for (int r = 0; r < 4; ++r) {
          float e = __builtin_amdgcn_exp2f(sc[kb][r]);
          ls += e;
          pw[r] = (bf16_t)e;
        }
        *reinterpret_cast<bf16x4_t*>(Pw + l15 * 64 + ((kb * 16 + lg * 4) ^ psw)) = pw;
      }
    }
    asm volatile("" ::: "memory");  // P write -> read order (per-wave, DS in-order)
    bf16x8 pf0 = ld_bf8(Pw + l15 * 64 + ((lg * 8) ^ psw));
    bf16x8 pf1 = ld_bf8(Pw + l15 * 64 + ((32 + lg * 8) ^ psw));

    __builtin_amdgcn_s_setprio(1);
#pragma unroll
    for (int n = 0; n < 4; ++n) {
      bf16x8 vf0 = ld_swz64(Vd[cur], n * 16 + l15, lg);
      bf16x8 vf1 = ld_swz64(Vd[cur], n * 16 + l15, 4 + lg);
      o[n] = __builtin_amdgcn_mfma_f32_16x16x32_bf16(pf0, vf0, o[n], 0, 0, 0);
      o[n] = __builtin_amdgcn_mfma_f32_16x16x32_bf16(pf1, vf1, o[n], 0, 0, 0);
    }
    __builtin_amdgcn_s_setprio(0);
  }

  ls += __shfl_xor(ls, 16);
  ls += __shfl_xor(ls, 32);
  float l0 = __shfl(ls, lg * 4 + 0);
  float l1 = __shfl(ls, lg * 4 + 1);
  float l2 = __shfl(ls, lg * 4 + 2);
  float l3 = __shfl(ls, lg * 4 + 3);
  float lsr[4] = {l0, l1, l2, l3};
#pragma unroll
  for (int r = 0; r < 4; ++r) {
    float inv = 1.f / lsr[r];
    int row = qrow + lg * 4 + r;
#pragma unroll
    for (int n = 0; n < 4; ++n)
      out[((size_t)b * S_LEN + row) * DM + h * HDIM + n * 16 + l15] = o[n][r] * inv;
  }
}

// ---- kernel 5: causal flash attention.
// LDS = Kd 16K + Vd 16K + P 8K = 40960 B. ----
__global__ __launch_bounds__(256, 4) void k_attn(const u16* __restrict__ Qb, const u16* __restrict__ Kb,
                                                 const u16* __restrict__ Vtb, float* __restrict__ out) {
  __shared__ u16 Kd[2][64 * 64];
  __shared__ u16 Vd[2][64 * 64];
  __shared__ u16 Plds[4][16 * 64];
  int j = blockIdx.x;
  int m = j >> 3;
  int x = m & 15;
  int bh = (j & 7) + 8 * (m >> 4);
  int tid = threadIdx.x, lane = tid & 63, w = tid >> 6;
  int b = bh >> 4, h = bh & 15;
  const u16* Qp = Qb + (size_t)bh * S_LEN * HDIM;
  const u16* Kp = Kb + (size_t)bh * S_LEN * HDIM;
  const u16* Vp = Vtb + (size_t)bh * HDIM * S_LEN;
  u16* Pw = Plds[w];
  attn_strip(Qp, Kp, Vp, out, b, h, x * 64, w, tid, lane, x + 1, Kd, Vd, Pw);
  attn_strip(Qp, Kp, Vp, out, b, h, (31 - x) * 64, w, tid, lane, 32 - x, Kd, Vd, Pw);
}

extern "C" void kernel_launch(void* const* d_in, const int* in_sizes, int n_in,
                              void* d_out, int out_size, void* d_ws, size_t ws_size,
                              hipStream_t stream) {
  const float* x  = (const float*)d_in[0];
  const float* Wq = (const float*)d_in[1];
  const float* Wk = (const float*)d_in[2];
  const float* Wv = (const float*)d_in[3];
  float* out = (float*)d_out;

  u16* ws  = (u16*)d_ws;
  u16* xb  = ws;                    // 8192*1024
  u16* wqt = xb + 8388608;          // 3 x 1024*1024 contiguous
  u16* Qb  = wqt + 3145728;         // Q,K each [B,H,S,HD]
  u16* Kb  = Qb + 8388608;
  u16* Vtb = Kb + 8388608;          // [B,H,HD,S] written directly by k_gemm

  const float qscale = 0.125f * 1.44269504088896f;  // 1/sqrt(64) * log2(e)

  k_cvt<<<8192, 256, 0, stream>>>(x, xb);
  k_wt3<<<dim3(32, 32, 3), 256, 0, stream>>>(Wq, Wk, Wv, wqt);
  k_gemm<<<dim3(24, 64), 256, 0, stream>>>(xb, wqt, Qb, Vtb, qscale);
  k_attn<<<1024, 256, 0, stream>>>(Qb, Kb, Vtb, out);
}